// Round 8
// baseline (247.100 us; speedup 1.0000x reference)
//
#include <hip/hip_runtime.h>
#include <hip/hip_fp16.h>
#include <math.h>

#define LQ 22223
#define NH 8
#define NL 4
#define NP 4
#define CDIM 256
#define MB128 174             // ceil(LQ/128)
#define NBV  352              // v-GEMM:   2 bx * 174 by, XCD-grouped (44*8)
#define NBOA 528              // oa-GEMM:  3 bx * 174 by, XCD-grouped (66*8)

typedef __attribute__((ext_vector_type(8))) short short8;
typedef __attribute__((ext_vector_type(4))) float f32x4;

__device__ __forceinline__ ushort f2bf(float f) {
    union { float f; unsigned u; } c; c.f = f;
    unsigned u = c.u;
    return (ushort)((u + 0x7fffu + ((u >> 16) & 1u)) >> 16);   // RNE
}
__device__ __forceinline__ float bflo(unsigned u) {
    union { unsigned u; float f; } c; c.u = u << 16; return c.f;
}
__device__ __forceinline__ float bfhi(unsigned u) {
    union { unsigned u; float f; } c; c.u = u & 0xffff0000u; return c.f;
}
__device__ __forceinline__ unsigned pack_h2(float a, float b) {
    union { __half2 h; unsigned u; } c; c.h = __floats2half2_rn(a, b); return c.u;
}
__device__ __forceinline__ float2 unpack_h2(unsigned u) {
    union { unsigned u; __half2 h; } c; c.u = u; return __half22float2(c.h);
}

// ---------------------------------------------------------------------------
// Transpose+convert weights fp32 [K=256][N] -> bf16 [N][K].
// Wt_oa = concat(W_off rows, W_attn rows); bcat = concat(b_off, b_attn).
// ---------------------------------------------------------------------------
__global__ __launch_bounds__(256) void convert_wt(
    const float* __restrict__ Wv, const float* __restrict__ Wo,
    const float* __restrict__ Wu, const float* __restrict__ Wa,
    const float* __restrict__ bo, const float* __restrict__ ba,
    ushort* __restrict__ Tv, ushort* __restrict__ Toa,
    ushort* __restrict__ Tu, float* __restrict__ bcat)
{
    int idx = blockIdx.x * 256 + threadIdx.x;
    if (idx >= 229376) {
        int b = idx - 229376;
        if (b < 384) bcat[b] = (b < 256) ? bo[b] : ba[b - 256];
        return;
    }
    const float* W; ushort* T; int N; int local;
    if      (idx < 65536)  { W = Wv; T = Tv;          N = 256; local = idx; }
    else if (idx < 131072) { W = Wo; T = Toa;         N = 256; local = idx - 65536; }
    else if (idx < 196608) { W = Wu; T = Tu;          N = 256; local = idx - 131072; }
    else                   { W = Wa; T = Toa + 65536; N = 128; local = idx - 196608; }
    int k = local & 255;
    int n = local >> 8;
    T[n * 256 + k] = f2bf(W[k * N + n]);
}

// ---------------------------------------------------------------------------
// Fused dual GEMM, 128x128 tiles, BK=32, XCD-swizzled.
//   blocks [0,NBV):   v_bf = bf16(value @ Wt_val^T + b_val)        N=256
//   blocks [NBV,..):  offattn = query @ Wt_oa^T + bcat   (fp32)    N=384
// oa tiles with bx==2 hold ALL logits (cols 256..383): head = t-frag,
// point = lane&15 -> softmax = shfl_xor max/sum over 16-lane groups, fused
// into the epilogue (kills the separate softmax16 dispatch).
// 4 waves, each 32 rows x 128 cols (2x8 fragment grid, 16 MFMA : 10 ds_read
// per iter). A fp32 converted to bf16 during staging.
// ---------------------------------------------------------------------------
__global__ __launch_bounds__(256) void gemm_dual(
    const float* __restrict__ value, const ushort* __restrict__ Wtv,
    const float* __restrict__ bv, ushort* __restrict__ Cv,
    const float* __restrict__ query, const ushort* __restrict__ Wtoa,
    const float* __restrict__ boa, float* __restrict__ Coa)
{
    __shared__ ushort As[128 * 40];
    __shared__ ushort Bs[128 * 40];

    const int b = blockIdx.x;
    const int xcd = b & 7;
    const float* A; const ushort* Bt; const float* bias;
    int N, bx, by; bool isv;
    if (b < NBV) {
        isv = true;  A = value; Bt = Wtv;  bias = bv;  N = 256;
        const int j = b >> 3;
        bx = j & 1;  by = xcd + 8 * (j >> 1);
    } else {
        isv = false; A = query; Bt = Wtoa; bias = boa; N = 384;
        const int j = (b - NBV) >> 3;
        bx = j % 3;  by = xcd + 8 * (j / 3);
    }
    if (by >= MB128) return;

    const int tid = threadIdx.x;
    const int w = tid >> 6;
    const int l = tid & 63;
    const int lr = l & 15;
    const int lk = (l >> 4) << 3;
    const int bm = by * 128;
    const int bn = bx * 128;

    const int sr = tid >> 1;           // staging row 0..127
    const int sc = (tid & 1) * 16;     // k-chunk 0 or 16

    const bool arow = (bm + sr) < LQ;
    const float*  Ap = A  + (size_t)(bm + sr) * 256 + sc;
    const ushort* Bp = Bt + (size_t)(bn + sr) * 256 + sc;

    f32x4 acc0[8] = {}, acc1[8] = {};

    for (int k0 = 0; k0 < 256; k0 += 32) {
        short8 a0 = {0,0,0,0,0,0,0,0}, a1 = {0,0,0,0,0,0,0,0};
        if (arow) {
            const float4 f0 = *reinterpret_cast<const float4*>(Ap + k0);
            const float4 f1 = *reinterpret_cast<const float4*>(Ap + k0 + 4);
            const float4 f2 = *reinterpret_cast<const float4*>(Ap + k0 + 8);
            const float4 f3 = *reinterpret_cast<const float4*>(Ap + k0 + 12);
            a0[0]=(short)f2bf(f0.x); a0[1]=(short)f2bf(f0.y);
            a0[2]=(short)f2bf(f0.z); a0[3]=(short)f2bf(f0.w);
            a0[4]=(short)f2bf(f1.x); a0[5]=(short)f2bf(f1.y);
            a0[6]=(short)f2bf(f1.z); a0[7]=(short)f2bf(f1.w);
            a1[0]=(short)f2bf(f2.x); a1[1]=(short)f2bf(f2.y);
            a1[2]=(short)f2bf(f2.z); a1[3]=(short)f2bf(f2.w);
            a1[4]=(short)f2bf(f3.x); a1[5]=(short)f2bf(f3.y);
            a1[6]=(short)f2bf(f3.z); a1[7]=(short)f2bf(f3.w);
        }
        const short8 b0 = *reinterpret_cast<const short8*>(Bp + k0);
        const short8 b1 = *reinterpret_cast<const short8*>(Bp + k0 + 8);

        __syncthreads();
        *reinterpret_cast<short8*>(&As[sr * 40 + sc])     = a0;
        *reinterpret_cast<short8*>(&As[sr * 40 + sc + 8]) = a1;
        *reinterpret_cast<short8*>(&Bs[sr * 40 + sc])     = b0;
        *reinterpret_cast<short8*>(&Bs[sr * 40 + sc + 8]) = b1;
        __syncthreads();

        const short8 af0 = *reinterpret_cast<const short8*>(&As[(w * 32 + lr) * 40 + lk]);
        const short8 af1 = *reinterpret_cast<const short8*>(&As[(w * 32 + 16 + lr) * 40 + lk]);
        #pragma unroll
        for (int t = 0; t < 8; ++t) {
            const short8 bf = *reinterpret_cast<const short8*>(&Bs[(t * 16 + lr) * 40 + lk]);
            acc0[t] = __builtin_amdgcn_mfma_f32_16x16x32_bf16(af0, bf, acc0[t], 0, 0, 0);
            acc1[t] = __builtin_amdgcn_mfma_f32_16x16x32_bf16(af1, bf, acc1[t], 0, 0, 0);
        }
    }

    // bias (per t-frag, col = bn + t*16 + lr)
    float bs[8];
    #pragma unroll
    for (int t = 0; t < 8; ++t) bs[t] = bias[bn + t * 16 + lr];

    const int rbase = bm + w * 32 + ((l >> 4) << 2);

    if (isv) {
        #pragma unroll
        for (int rf = 0; rf < 2; ++rf) {
            f32x4* acc = rf ? acc1 : acc0;
            #pragma unroll
            for (int t = 0; t < 8; ++t) {
                const int col = bn + t * 16 + lr;
                #pragma unroll
                for (int i = 0; i < 4; ++i) {
                    const int row = rbase + rf * 16 + i;
                    if (row < LQ) Cv[(size_t)row * 256 + col] = f2bf(acc[t][i] + bs[t]);
                }
            }
        }
    } else {
        if (bx == 2) {
            // fused softmax: head = t, point = lr; reduce over 16-lane groups
            #pragma unroll
            for (int rf = 0; rf < 2; ++rf) {
                f32x4* acc = rf ? acc1 : acc0;
                #pragma unroll
                for (int t = 0; t < 8; ++t) {
                    #pragma unroll
                    for (int i = 0; i < 4; ++i) {
                        float x = acc[t][i] + bs[t];
                        float m = x;
                        m = fmaxf(m, __shfl_xor(m, 1));
                        m = fmaxf(m, __shfl_xor(m, 2));
                        m = fmaxf(m, __shfl_xor(m, 4));
                        m = fmaxf(m, __shfl_xor(m, 8));
                        const float e = expf(x - m);
                        float s = e;
                        s += __shfl_xor(s, 1);
                        s += __shfl_xor(s, 2);
                        s += __shfl_xor(s, 4);
                        s += __shfl_xor(s, 8);
                        acc[t][i] = e / s;
                    }
                }
            }
            #pragma unroll
            for (int rf = 0; rf < 2; ++rf) {
                f32x4* acc = rf ? acc1 : acc0;
                #pragma unroll
                for (int t = 0; t < 8; ++t) {
                    const int col = bn + t * 16 + lr;
                    #pragma unroll
                    for (int i = 0; i < 4; ++i) {
                        const int row = rbase + rf * 16 + i;
                        if (row < LQ) Coa[(size_t)row * 384 + col] = acc[t][i];
                    }
                }
            }
        } else {
            #pragma unroll
            for (int rf = 0; rf < 2; ++rf) {
                f32x4* acc = rf ? acc1 : acc0;
                #pragma unroll
                for (int t = 0; t < 8; ++t) {
                    const int col = bn + t * 16 + lr;
                    #pragma unroll
                    for (int i = 0; i < 4; ++i) {
                        const int row = rbase + rf * 16 + i;
                        if (row < LQ) Coa[(size_t)row * 384 + col] = acc[t][i] + bs[t];
                    }
                }
            }
        }
    }
}

// ---------------------------------------------------------------------------
// Output GEMM, 128x128 tile, bf16 A, fp32 out. Same swizzle. N=256.
// ---------------------------------------------------------------------------
__global__ __launch_bounds__(256) void gemm_out(
    const ushort* __restrict__ A, const ushort* __restrict__ Bt,
    const float* __restrict__ bias, float* __restrict__ C)
{
    __shared__ ushort As[128 * 40];
    __shared__ ushort Bs[128 * 40];

    const int b = blockIdx.x;
    const int xcd = b & 7;
    const int j = b >> 3;
    const int bx = j & 1;
    const int by = xcd + 8 * (j >> 1);
    if (by >= MB128) return;

    const int tid = threadIdx.x;
    const int w = tid >> 6;
    const int l = tid & 63;
    const int lr = l & 15;
    const int lk = (l >> 4) << 3;
    const int bm = by * 128;
    const int bn = bx * 128;

    const int sr = tid >> 1;
    const int sc = (tid & 1) * 16;

    const bool arow = (bm + sr) < LQ;
    const ushort* Ap = A  + (size_t)(bm + sr) * 256 + sc;
    const ushort* Bp = Bt + (size_t)(bn + sr) * 256 + sc;

    f32x4 acc0[8] = {}, acc1[8] = {};

    for (int k0 = 0; k0 < 256; k0 += 32) {
        short8 a0 = {0,0,0,0,0,0,0,0}, a1 = {0,0,0,0,0,0,0,0};
        if (arow) {
            a0 = *reinterpret_cast<const short8*>(Ap + k0);
            a1 = *reinterpret_cast<const short8*>(Ap + k0 + 8);
        }
        const short8 b0 = *reinterpret_cast<const short8*>(Bp + k0);
        const short8 b1 = *reinterpret_cast<const short8*>(Bp + k0 + 8);

        __syncthreads();
        *reinterpret_cast<short8*>(&As[sr * 40 + sc])     = a0;
        *reinterpret_cast<short8*>(&As[sr * 40 + sc + 8]) = a1;
        *reinterpret_cast<short8*>(&Bs[sr * 40 + sc])     = b0;
        *reinterpret_cast<short8*>(&Bs[sr * 40 + sc + 8]) = b1;
        __syncthreads();

        const short8 af0 = *reinterpret_cast<const short8*>(&As[(w * 32 + lr) * 40 + lk]);
        const short8 af1 = *reinterpret_cast<const short8*>(&As[(w * 32 + 16 + lr) * 40 + lk]);
        #pragma unroll
        for (int t = 0; t < 8; ++t) {
            const short8 bf = *reinterpret_cast<const short8*>(&Bs[(t * 16 + lr) * 40 + lk]);
            acc0[t] = __builtin_amdgcn_mfma_f32_16x16x32_bf16(af0, bf, acc0[t], 0, 0, 0);
            acc1[t] = __builtin_amdgcn_mfma_f32_16x16x32_bf16(af1, bf, acc1[t], 0, 0, 0);
        }
    }

    const int rbase = bm + w * 32 + ((l >> 4) << 2);
    #pragma unroll
    for (int rf = 0; rf < 2; ++rf) {
        f32x4* acc = rf ? acc1 : acc0;
        #pragma unroll
        for (int t = 0; t < 8; ++t) {
            const int col = bn + t * 16 + lr;
            const float bsv = bias[col];
            #pragma unroll
            for (int i = 0; i < 4; ++i) {
                const int row = rbase + rf * 16 + i;
                if (row < LQ) C[(size_t)row * 256 + col] = acc[t][i] + bsv;
            }
        }
    }
}

// ---------------------------------------------------------------------------
// Multi-scale deformable sampling over bf16 value.
//   block = 64 q x 4 lanes (8 bf16 channels each), one head.
//   blockIdx.x = qg*8 + h -> head-pinned to XCDs (per-head slice 1.42 MB).
// LDS 16 KB (int2 base+packed-deltas, fp16-packed weights) -> wave-cap
// 8 blocks/CU = 32 waves (~2x round 7's occupancy; this kernel is
// L2-latency bound and needs TLP). launch_bounds(256,8) caps VGPR at 64.
// ---------------------------------------------------------------------------
__global__ __launch_bounds__(256, 8) void msda_sample(
    const ushort* __restrict__ v, const float* __restrict__ offattn,
    const float* __restrict__ ref, ushort* __restrict__ outp)
{
    __shared__ int2  s_off[1024];   // [p*64+qi]: {base<<8|h32, dx | dy<<16}
    __shared__ uint2 s_wts[1024];   // 4 x fp16 folded corner weights

    const int h = blockIdx.x & 7;
    const int qbase = (blockIdx.x >> 3) * 64;
    const int tid = threadIdx.x;

    const int Hs[4] = {100, 50, 25, 13};
    const int Ws[4] = {167, 84, 42, 21};
    const int starts[4] = {0, 16700, 20900, 21950};
    const int h32 = h * 32;

    // ---- Phase 1 ----
    #pragma unroll
    for (int t2 = 0; t2 < 4; ++t2) {
        const int t = t2 * 256 + tid;     // = pi*64 + qi
        const int qi = t & 63;
        const int pi = t >> 6;            // 0..15
        const int q = qbase + qi;
        if (q < LQ) {
            const int l = pi >> 2;
            const int W = Ws[l], H = Hs[l];
            const float* refq = ref + (size_t)q * (NL * 4) + l * 4;
            const float cx = refq[0], cy = refq[1], rw = refq[2], rh = refq[3];
            const float* row = offattn + (size_t)q * 384;
            const float ox  = row[h32 + pi * 2];
            const float oy  = row[h32 + pi * 2 + 1];
            const float wgt = row[256 + h * 16 + pi];

            const float lx = cx + ox * 0.125f * rw;
            const float ly = cy + oy * 0.125f * rh;
            const float x = lx * (float)W - 0.5f;
            const float y = ly * (float)H - 0.5f;

            const float x0f = floorf(x);
            const float y0f = floorf(y);
            const int x0 = (int)x0f, y0 = (int)y0f;
            const float wx1 = x - x0f, wy1 = y - y0f;
            const float wx0 = 1.f - wx1, wy0 = 1.f - wy1;

            const bool xv0 = (x0 >= 0) && (x0 < W);
            const bool xv1 = (x0 + 1 >= 0) && (x0 + 1 < W);
            const bool yv0 = (y0 >= 0) && (y0 < H);
            const bool yv1 = (y0 + 1 >= 0) && (y0 + 1 < H);

            const int x0c = min(max(x0, 0), W - 1);
            const int x1c = min(max(x0 + 1, 0), W - 1);
            const int y0c = min(max(y0, 0), H - 1);
            const int y1c = min(max(y0 + 1, 0), H - 1);

            const int base = ((starts[l] + y0c * W + x0c) << 8) + h32;
            const int dx = (x1c - x0c) << 8;            // 0 or 256
            const int dy = ((y1c - y0c) * W) << 8;      // 0..42752, fits 16b
            const float w00 = (xv0 && yv0) ? wgt * wy0 * wx0 : 0.f;
            const float w01 = (xv1 && yv0) ? wgt * wy0 * wx1 : 0.f;
            const float w10 = (xv0 && yv1) ? wgt * wy1 * wx0 : 0.f;
            const float w11 = (xv1 && yv1) ? wgt * wy1 * wx1 : 0.f;
            s_off[t] = make_int2(base, dx | (dy << 16));
            s_wts[t] = make_uint2(pack_h2(w00, w01), pack_h2(w10, w11));
        }
    }
    __syncthreads();

    // ---- Phase 2 ----
    const int qi = tid >> 2;          // 0..63
    const int dg = tid & 3;           // channel group (8 bf16)
    const int q = qbase + qi;
    if (q >= LQ) return;
    const int d8 = dg * 8;

    float acc[8] = {};

    #pragma unroll 4
    for (int p = 0; p < 16; ++p) {
        const int2  ob = s_off[p * 64 + qi];
        const uint2 wp = s_wts[p * 64 + qi];
        const ushort* base = v + ob.x + d8;
        const int dx = ob.y & 0xffff;
        const int dy = ((unsigned)ob.y) >> 16;
        const uint4 a0 = *reinterpret_cast<const uint4*>(base);
        const uint4 a1 = *reinterpret_cast<const uint4*>(base + dx);
        const uint4 a2 = *reinterpret_cast<const uint4*>(base + dy);
        const uint4 a3 = *reinterpret_cast<const uint4*>(base + dx + dy);
        const float2 wA = unpack_h2(wp.x);   // w00, w01
        const float2 wB = unpack_h2(wp.y);   // w10, w11
        const unsigned u0[4] = {a0.x, a0.y, a0.z, a0.w};
        const unsigned u1[4] = {a1.x, a1.y, a1.z, a1.w};
        const unsigned u2[4] = {a2.x, a2.y, a2.z, a2.w};
        const unsigned u3[4] = {a3.x, a3.y, a3.z, a3.w};
        #pragma unroll
        for (int j = 0; j < 4; ++j) {
            acc[2 * j]     += wA.x * bflo(u0[j]) + wA.y * bflo(u1[j])
                            + wB.x * bflo(u2[j]) + wB.y * bflo(u3[j]);
            acc[2 * j + 1] += wA.x * bfhi(u0[j]) + wA.y * bfhi(u1[j])
                            + wB.x * bfhi(u2[j]) + wB.y * bfhi(u3[j]);
        }
    }

    short8 o8;
    #pragma unroll
    for (int j = 0; j < 8; ++j) o8[j] = (short)f2bf(acc[j]);
    *reinterpret_cast<short8*>(outp + (size_t)q * CDIM + h32 + d8) = o8;
}

// ---------------------------------------------------------------------------
extern "C" void kernel_launch(void* const* d_in, const int* in_sizes, int n_in,
                              void* d_out, int out_size, void* d_ws, size_t ws_size,
                              hipStream_t stream)
{
    const float* query  = (const float*)d_in[0];
    const float* ref    = (const float*)d_in[1];
    const float* value  = (const float*)d_in[2];
    const float* W_off  = (const float*)d_in[3];
    const float* b_off  = (const float*)d_in[4];
    const float* W_attn = (const float*)d_in[5];
    const float* b_attn = (const float*)d_in[6];
    const float* W_val  = (const float*)d_in[7];
    const float* b_val  = (const float*)d_in[8];
    const float* W_out  = (const float*)d_in[9];
    const float* b_out  = (const float*)d_in[10];
    float* out = (float*)d_out;

    char* p = (char*)d_ws;
    ushort* v_bf    = (ushort*)p; p += (size_t)LQ * CDIM * 2;   // bf16 value'
    float*  offattn = (float*)p;  p += (size_t)LQ * 384 * 4;    // softmaxed attn inside
    ushort* outp    = (ushort*)p; p += (size_t)LQ * CDIM * 2;   // bf16 sampled
    ushort* Wt_val  = (ushort*)p; p += 65536 * 2;
    ushort* Wt_oa   = (ushort*)p; p += (65536 + 32768) * 2;
    ushort* Wt_out  = (ushort*)p; p += 65536 * 2;
    float*  bcat    = (float*)p;  p += 384 * 4;

    // 1. weights fp32 -> bf16 [N][K] (+ concatenated off/attn bias)
    convert_wt<<<(229376 + 384 + 255) / 256, 256, 0, stream>>>(
        W_val, W_off, W_out, W_attn, b_off, b_attn, Wt_val, Wt_oa, Wt_out, bcat);

    // 2. fused: v_bf = bf16(value@Wv+bv)  AND  offattn = query@Woa+bcat
    //    (softmax fused into the bx==2 logit tiles' epilogue)
    gemm_dual<<<NBV + NBOA, 256, 0, stream>>>(
        value, Wt_val, b_val, v_bf, query, Wt_oa, bcat, offattn);

    // 3. deformable sampling -> outp (bf16)
    const int qg = (LQ + 63) / 64;    // 348
    msda_sample<<<qg * 8, 256, 0, stream>>>(v_bf, offattn, ref, outp);

    // 4. out = outp @ W_out + b_out
    gemm_out<<<NBV, 256, 0, stream>>>(outp, Wt_out, b_out, out);
}

// Round 9
// 225.157 us; speedup vs baseline: 1.0975x; 1.0975x over previous
//
#include <hip/hip_runtime.h>
#include <math.h>

#define LQ 22223
#define NH 8
#define NL 4
#define NP 4
#define CDIM 256
#define MB128 174             // ceil(LQ/128)
// XCD-swizzled: b&7 = xcd, j=b>>3; bx = j%nbx, by = xcd + 8*(j/nbx)
#define NBV  (8 * 4 * 22)     // 704:  v-GEMM  (N=256, nbx=4, 22 by-groups)
#define NBOA (8 * 6 * 22)     // 1056: oa-GEMM (N=384, nbx=6)

typedef __attribute__((ext_vector_type(8))) short short8;
typedef __attribute__((ext_vector_type(4))) float f32x4;

__device__ __forceinline__ ushort f2bf(float f) {
    union { float f; unsigned u; } c; c.f = f;
    unsigned u = c.u;
    return (ushort)((u + 0x7fffu + ((u >> 16) & 1u)) >> 16);   // RNE
}
__device__ __forceinline__ float bflo(unsigned u) {
    union { unsigned u; float f; } c; c.u = u << 16; return c.f;
}
__device__ __forceinline__ float bfhi(unsigned u) {
    union { unsigned u; float f; } c; c.u = u & 0xffff0000u; return c.f;
}

// ---------------------------------------------------------------------------
// Transpose+convert weights fp32 [K=256][N] -> bf16 [N][K].
// Wt_oa = concat(W_off rows, W_attn rows); bcat = concat(b_off, b_attn).
// ---------------------------------------------------------------------------
__global__ __launch_bounds__(256) void convert_wt(
    const float* __restrict__ Wv, const float* __restrict__ Wo,
    const float* __restrict__ Wu, const float* __restrict__ Wa,
    const float* __restrict__ bo, const float* __restrict__ ba,
    ushort* __restrict__ Tv, ushort* __restrict__ Toa,
    ushort* __restrict__ Tu, float* __restrict__ bcat)
{
    int idx = blockIdx.x * 256 + threadIdx.x;
    if (idx >= 229376) {
        int b = idx - 229376;
        if (b < 384) bcat[b] = (b < 256) ? bo[b] : ba[b - 256];
        return;
    }
    const float* W; ushort* T; int N; int local;
    if      (idx < 65536)  { W = Wv; T = Tv;          N = 256; local = idx; }
    else if (idx < 131072) { W = Wo; T = Toa;         N = 256; local = idx - 65536; }
    else if (idx < 196608) { W = Wu; T = Tu;          N = 256; local = idx - 131072; }
    else                   { W = Wa; T = Toa + 65536; N = 128; local = idx - 196608; }
    int k = local & 255;
    int n = local >> 8;
    T[n * 256 + k] = f2bf(W[k * N + n]);
}

// ---------------------------------------------------------------------------
// Fused dual GEMM: 128x64 tiles, BK=32, XCD-swizzled, LDS double-buffered
// (the R7-proven pattern: prefetch to regs post-barrier, write alt bank
// after MFMAs -> one barrier per K-iter).
//   blocks [0,NBV):   v_bf = bf16(value @ Wt_val^T + b_val)        N=256
//   blocks [NBV,..):  offattn = query @ Wt_oa^T + bcat   (fp32)    N=384
// oa tiles with bn>=256 hold logits: head = (bn-256)/16 + t, point = l&15
// -> softmax fused via shfl_xor over 16-lane groups (no separate dispatch).
// 4 waves x (32 rows x 64 cols): 8 accs, 8 MFMA : 6 ds_read_b128 per iter.
// ---------------------------------------------------------------------------
__global__ __launch_bounds__(256, 5) void gemm_dual(
    const float* __restrict__ value, const ushort* __restrict__ Wtv,
    const float* __restrict__ bv, ushort* __restrict__ Cv,
    const float* __restrict__ query, const ushort* __restrict__ Wtoa,
    const float* __restrict__ boa, float* __restrict__ Coa)
{
    __shared__ ushort As[2][128 * 40];
    __shared__ ushort Bs[2][64 * 40];

    const int b = blockIdx.x;
    const int xcd = b & 7;
    const float* A; const ushort* Bt; const float* bias;
    int N, bx, by; bool isv;
    if (b < NBV) {
        isv = true;  A = value; Bt = Wtv;  bias = bv;  N = 256;
        const int j = b >> 3;
        bx = j & 3;  by = xcd + 8 * (j >> 2);
    } else {
        isv = false; A = query; Bt = Wtoa; bias = boa; N = 384;
        const int j = (b - NBV) >> 3;
        bx = j % 6;  by = xcd + 8 * (j / 6);
    }
    if (by >= MB128) return;

    const int tid = threadIdx.x;
    const int w = tid >> 6;
    const int l = tid & 63;
    const int lr = l & 15;
    const int lk = (l >> 4) << 3;
    const int bm = by * 128;
    const int bn = bx * 64;

    // A staging: 128 rows x 32 k; thread: row ra = tid>>1, 16 elems at ca
    const int ra = tid >> 1;
    const int ca = (tid & 1) * 16;
    // B staging: 64 rows x 32 k; thread: row rb = tid>>2, 8 elems at cb
    const int rb = tid >> 2;
    const int cb = (tid & 3) * 8;

    const bool arow = (bm + ra) < LQ;
    const float*  Ap = A  + (size_t)(bm + ra) * 256 + ca;
    const ushort* Bp = Bt + (size_t)(bn + rb) * 256 + cb;

    auto ldA = [&](int k0, short8& a0, short8& a1) {
        a0 = short8{0,0,0,0,0,0,0,0}; a1 = short8{0,0,0,0,0,0,0,0};
        if (arow) {
            const float4 f0 = *reinterpret_cast<const float4*>(Ap + k0);
            const float4 f1 = *reinterpret_cast<const float4*>(Ap + k0 + 4);
            const float4 f2 = *reinterpret_cast<const float4*>(Ap + k0 + 8);
            const float4 f3 = *reinterpret_cast<const float4*>(Ap + k0 + 12);
            a0[0]=(short)f2bf(f0.x); a0[1]=(short)f2bf(f0.y);
            a0[2]=(short)f2bf(f0.z); a0[3]=(short)f2bf(f0.w);
            a0[4]=(short)f2bf(f1.x); a0[5]=(short)f2bf(f1.y);
            a0[6]=(short)f2bf(f1.z); a0[7]=(short)f2bf(f1.w);
            a1[0]=(short)f2bf(f2.x); a1[1]=(short)f2bf(f2.y);
            a1[2]=(short)f2bf(f2.z); a1[3]=(short)f2bf(f2.w);
            a1[4]=(short)f2bf(f3.x); a1[5]=(short)f2bf(f3.y);
            a1[6]=(short)f2bf(f3.z); a1[7]=(short)f2bf(f3.w);
        }
    };

    short8 a0, a1, bvv;
    ldA(0, a0, a1);
    bvv = *reinterpret_cast<const short8*>(Bp);
    *reinterpret_cast<short8*>(&As[0][ra * 40 + ca])     = a0;
    *reinterpret_cast<short8*>(&As[0][ra * 40 + ca + 8]) = a1;
    *reinterpret_cast<short8*>(&Bs[0][rb * 40 + cb])     = bvv;

    f32x4 acc[2][4] = {};

    #pragma unroll
    for (int k = 0; k < 8; ++k) {
        __syncthreads();
        if (k < 7) {
            ldA((k + 1) * 32, a0, a1);
            bvv = *reinterpret_cast<const short8*>(Bp + (k + 1) * 32);
        }
        const int cur = k & 1;
        const short8 af0 = *reinterpret_cast<const short8*>(
            &As[cur][(w * 32 + lr) * 40 + lk]);
        const short8 af1 = *reinterpret_cast<const short8*>(
            &As[cur][(w * 32 + 16 + lr) * 40 + lk]);
        #pragma unroll
        for (int t = 0; t < 4; ++t) {
            const short8 bf = *reinterpret_cast<const short8*>(
                &Bs[cur][(t * 16 + lr) * 40 + lk]);
            acc[0][t] = __builtin_amdgcn_mfma_f32_16x16x32_bf16(af0, bf, acc[0][t], 0, 0, 0);
            acc[1][t] = __builtin_amdgcn_mfma_f32_16x16x32_bf16(af1, bf, acc[1][t], 0, 0, 0);
        }
        if (k < 7) {
            const int nxt = cur ^ 1;
            *reinterpret_cast<short8*>(&As[nxt][ra * 40 + ca])     = a0;
            *reinterpret_cast<short8*>(&As[nxt][ra * 40 + ca + 8]) = a1;
            *reinterpret_cast<short8*>(&Bs[nxt][rb * 40 + cb])     = bvv;
        }
    }

    const int rbase = bm + w * 32 + ((l >> 4) << 2);
    const bool do_sm = (!isv) && (bn >= 256);   // logit tile -> fused softmax

    #pragma unroll
    for (int rf = 0; rf < 2; ++rf) {
        #pragma unroll
        for (int t = 0; t < 4; ++t) {
            const int col = bn + t * 16 + lr;
            const float bs = bias[col];
            #pragma unroll
            for (int i = 0; i < 4; ++i) {
                const int row = rbase + rf * 16 + i;
                float x = acc[rf][t][i] + bs;
                if (do_sm) {
                    float m = x;
                    m = fmaxf(m, __shfl_xor(m, 1));
                    m = fmaxf(m, __shfl_xor(m, 2));
                    m = fmaxf(m, __shfl_xor(m, 4));
                    m = fmaxf(m, __shfl_xor(m, 8));
                    const float e = expf(x - m);
                    float s = e;
                    s += __shfl_xor(s, 1);
                    s += __shfl_xor(s, 2);
                    s += __shfl_xor(s, 4);
                    s += __shfl_xor(s, 8);
                    x = e / s;
                }
                if (row < LQ) {
                    if (isv) Cv[(size_t)row * 256 + col] = f2bf(x);
                    else     Coa[(size_t)row * 384 + col] = x;
                }
            }
        }
    }
}

// ---------------------------------------------------------------------------
// Output GEMM: 128x64 tile, bf16 A, fp32 out, dbuf + swizzle. N=256.
// ---------------------------------------------------------------------------
__global__ __launch_bounds__(256, 5) void gemm_out(
    const ushort* __restrict__ A, const ushort* __restrict__ Bt,
    const float* __restrict__ bias, float* __restrict__ C)
{
    __shared__ ushort As[2][128 * 40];
    __shared__ ushort Bs[2][64 * 40];

    const int b = blockIdx.x;
    const int xcd = b & 7;
    const int j = b >> 3;
    const int bx = j & 3;
    const int by = xcd + 8 * (j >> 2);
    if (by >= MB128) return;

    const int tid = threadIdx.x;
    const int w = tid >> 6;
    const int l = tid & 63;
    const int lr = l & 15;
    const int lk = (l >> 4) << 3;
    const int bm = by * 128;
    const int bn = bx * 64;

    const int ra = tid >> 1;
    const int ca = (tid & 1) * 16;
    const int rb = tid >> 2;
    const int cb = (tid & 3) * 8;

    const bool arow = (bm + ra) < LQ;
    const ushort* Ap = A  + (size_t)(bm + ra) * 256 + ca;
    const ushort* Bp = Bt + (size_t)(bn + rb) * 256 + cb;

    auto ldA = [&](int k0, short8& x0, short8& x1) {
        x0 = short8{0,0,0,0,0,0,0,0}; x1 = short8{0,0,0,0,0,0,0,0};
        if (arow) {
            x0 = *reinterpret_cast<const short8*>(Ap + k0);
            x1 = *reinterpret_cast<const short8*>(Ap + k0 + 8);
        }
    };

    short8 a0, a1, bvv;
    ldA(0, a0, a1);
    bvv = *reinterpret_cast<const short8*>(Bp);
    *reinterpret_cast<short8*>(&As[0][ra * 40 + ca])     = a0;
    *reinterpret_cast<short8*>(&As[0][ra * 40 + ca + 8]) = a1;
    *reinterpret_cast<short8*>(&Bs[0][rb * 40 + cb])     = bvv;

    f32x4 acc[2][4] = {};

    #pragma unroll
    for (int k = 0; k < 8; ++k) {
        __syncthreads();
        if (k < 7) {
            ldA((k + 1) * 32, a0, a1);
            bvv = *reinterpret_cast<const short8*>(Bp + (k + 1) * 32);
        }
        const int cur = k & 1;
        const short8 af0 = *reinterpret_cast<const short8*>(
            &As[cur][(w * 32 + lr) * 40 + lk]);
        const short8 af1 = *reinterpret_cast<const short8*>(
            &As[cur][(w * 32 + 16 + lr) * 40 + lk]);
        #pragma unroll
        for (int t = 0; t < 4; ++t) {
            const short8 bf = *reinterpret_cast<const short8*>(
                &Bs[cur][(t * 16 + lr) * 40 + lk]);
            acc[0][t] = __builtin_amdgcn_mfma_f32_16x16x32_bf16(af0, bf, acc[0][t], 0, 0, 0);
            acc[1][t] = __builtin_amdgcn_mfma_f32_16x16x32_bf16(af1, bf, acc[1][t], 0, 0, 0);
        }
        if (k < 7) {
            const int nxt = cur ^ 1;
            *reinterpret_cast<short8*>(&As[nxt][ra * 40 + ca])     = a0;
            *reinterpret_cast<short8*>(&As[nxt][ra * 40 + ca + 8]) = a1;
            *reinterpret_cast<short8*>(&Bs[nxt][rb * 40 + cb])     = bvv;
        }
    }

    const int rbase = bm + w * 32 + ((l >> 4) << 2);
    #pragma unroll
    for (int rf = 0; rf < 2; ++rf) {
        #pragma unroll
        for (int t = 0; t < 4; ++t) {
            const int col = bn + t * 16 + lr;
            const float bs = bias[col];
            #pragma unroll
            for (int i = 0; i < 4; ++i) {
                const int row = rbase + rf * 16 + i;
                if (row < LQ) C[(size_t)row * 256 + col] = acc[rf][t][i] + bs;
            }
        }
    }
}

// ---------------------------------------------------------------------------
// Multi-scale deformable sampling over bf16 value — R7's proven version.
// block = 64 q x 4 lanes (8 bf16 channels each), one head; head-pinned via
// blockIdx.x = qg*8 + h. ~74 µs = TA scattered-segment-rate wall (measured
// invariant across occupancy 10-59% and bytes 0.7-1.4 GB, rounds 3-8).
// ---------------------------------------------------------------------------
__global__ __launch_bounds__(256, 5) void msda_sample(
    const ushort* __restrict__ v, const float* __restrict__ offattn,
    const float* __restrict__ ref, ushort* __restrict__ outp)
{
    __shared__ int4   s_off[1024];   // [p*64 + qi], element offsets into v
    __shared__ float4 s_wts[1024];

    const int h = blockIdx.x & 7;
    const int qbase = (blockIdx.x >> 3) * 64;
    const int tid = threadIdx.x;

    const int Hs[4] = {100, 50, 25, 13};
    const int Ws[4] = {167, 84, 42, 21};
    const int starts[4] = {0, 16700, 20900, 21950};
    const int h32 = h * 32;

    // ---- Phase 1 ----
    #pragma unroll
    for (int t2 = 0; t2 < 4; ++t2) {
        const int t = t2 * 256 + tid;     // = pi*64 + qi
        const int qi = t & 63;
        const int pi = t >> 6;            // 0..15
        const int q = qbase + qi;
        if (q < LQ) {
            const int l = pi >> 2;
            const int W = Ws[l], H = Hs[l];
            const float* refq = ref + (size_t)q * (NL * 4) + l * 4;
            const float cx = refq[0], cy = refq[1], rw = refq[2], rh = refq[3];
            const float* row = offattn + (size_t)q * 384;
            const float ox  = row[h32 + pi * 2];
            const float oy  = row[h32 + pi * 2 + 1];
            const float wgt = row[256 + h * 16 + pi];

            const float lx = cx + ox * 0.125f * rw;
            const float ly = cy + oy * 0.125f * rh;
            const float x = lx * (float)W - 0.5f;
            const float y = ly * (float)H - 0.5f;

            const float x0f = floorf(x);
            const float y0f = floorf(y);
            const int x0 = (int)x0f, y0 = (int)y0f;
            const float wx1 = x - x0f, wy1 = y - y0f;
            const float wx0 = 1.f - wx1, wy0 = 1.f - wy1;

            const bool xv0 = (x0 >= 0) && (x0 < W);
            const bool xv1 = (x0 + 1 >= 0) && (x0 + 1 < W);
            const bool yv0 = (y0 >= 0) && (y0 < H);
            const bool yv1 = (y0 + 1 >= 0) && (y0 + 1 < H);

            const int x0c = min(max(x0, 0), W - 1);
            const int x1c = min(max(x0 + 1, 0), W - 1);
            const int y0c = min(max(y0, 0), H - 1);
            const int y1c = min(max(y0 + 1, 0), H - 1);

            int4 ob;
            ob.x = ((starts[l] + y0c * W + x0c) << 8) + h32;
            ob.y = ((starts[l] + y0c * W + x1c) << 8) + h32;
            ob.z = ((starts[l] + y1c * W + x0c) << 8) + h32;
            ob.w = ((starts[l] + y1c * W + x1c) << 8) + h32;
            float4 wb;
            wb.x = (xv0 && yv0) ? wgt * wy0 * wx0 : 0.f;
            wb.y = (xv1 && yv0) ? wgt * wy0 * wx1 : 0.f;
            wb.z = (xv0 && yv1) ? wgt * wy1 * wx0 : 0.f;
            wb.w = (xv1 && yv1) ? wgt * wy1 * wx1 : 0.f;
            s_off[t] = ob;
            s_wts[t] = wb;
        }
    }
    __syncthreads();

    // ---- Phase 2 ----
    const int qi = tid >> 2;          // 0..63
    const int dg = tid & 3;           // channel group (8 bf16)
    const int q = qbase + qi;
    if (q >= LQ) return;
    const int d8 = dg * 8;

    float acc[8] = {};

    #pragma unroll 4
    for (int p = 0; p < 16; ++p) {
        const int4   o = s_off[p * 64 + qi];
        const float4 w = s_wts[p * 64 + qi];
        const uint4 a0 = *reinterpret_cast<const uint4*>(v + o.x + d8);
        const uint4 a1 = *reinterpret_cast<const uint4*>(v + o.y + d8);
        const uint4 a2 = *reinterpret_cast<const uint4*>(v + o.z + d8);
        const uint4 a3 = *reinterpret_cast<const uint4*>(v + o.w + d8);
        const unsigned u0[4] = {a0.x, a0.y, a0.z, a0.w};
        const unsigned u1[4] = {a1.x, a1.y, a1.z, a1.w};
        const unsigned u2[4] = {a2.x, a2.y, a2.z, a2.w};
        const unsigned u3[4] = {a3.x, a3.y, a3.z, a3.w};
        #pragma unroll
        for (int j = 0; j < 4; ++j) {
            acc[2 * j]     += w.x * bflo(u0[j]) + w.y * bflo(u1[j])
                            + w.z * bflo(u2[j]) + w.w * bflo(u3[j]);
            acc[2 * j + 1] += w.x * bfhi(u0[j]) + w.y * bfhi(u1[j])
                            + w.z * bfhi(u2[j]) + w.w * bfhi(u3[j]);
        }
    }

    short8 o8;
    #pragma unroll
    for (int j = 0; j < 8; ++j) o8[j] = (short)f2bf(acc[j]);
    *reinterpret_cast<short8*>(outp + (size_t)q * CDIM + h32 + d8) = o8;
}

// ---------------------------------------------------------------------------
extern "C" void kernel_launch(void* const* d_in, const int* in_sizes, int n_in,
                              void* d_out, int out_size, void* d_ws, size_t ws_size,
                              hipStream_t stream)
{
    const float* query  = (const float*)d_in[0];
    const float* ref    = (const float*)d_in[1];
    const float* value  = (const float*)d_in[2];
    const float* W_off  = (const float*)d_in[3];
    const float* b_off  = (const float*)d_in[4];
    const float* W_attn = (const float*)d_in[5];
    const float* b_attn = (const float*)d_in[6];
    const float* W_val  = (const float*)d_in[7];
    const float* b_val  = (const float*)d_in[8];
    const float* W_out  = (const float*)d_in[9];
    const float* b_out  = (const float*)d_in[10];
    float* out = (float*)d_out;

    char* p = (char*)d_ws;
    ushort* v_bf    = (ushort*)p; p += (size_t)LQ * CDIM * 2;   // bf16 value'
    float*  offattn = (float*)p;  p += (size_t)LQ * 384 * 4;    // softmaxed attn inside
    ushort* outp    = (ushort*)p; p += (size_t)LQ * CDIM * 2;   // bf16 sampled
    ushort* Wt_val  = (ushort*)p; p += 65536 * 2;
    ushort* Wt_oa   = (ushort*)p; p += (65536 + 32768) * 2;
    ushort* Wt_out  = (ushort*)p; p += 65536 * 2;
    float*  bcat    = (float*)p;  p += 384 * 4;

    // 1. weights fp32 -> bf16 [N][K] (+ concatenated off/attn bias)
    convert_wt<<<(229376 + 384 + 255) / 256, 256, 0, stream>>>(
        W_val, W_off, W_out, W_attn, b_off, b_attn, Wt_val, Wt_oa, Wt_out, bcat);

    // 2. fused: v_bf = bf16(value@Wv+bv) AND offattn = query@Woa+bcat
    //    (softmax fused into logit tiles' epilogue via shfl)
    gemm_dual<<<NBV + NBOA, 256, 0, stream>>>(
        value, Wt_val, b_val, v_bf, query, Wt_oa, bcat, offattn);

    // 3. deformable sampling -> outp (bf16)
    const int qg = (LQ + 63) / 64;    // 348
    msda_sample<<<qg * 8, 256, 0, stream>>>(v_bf, offattn, ref, outp);

    // 4. out = outp @ W_out + b_out
    gemm_out<<<NBV, 256, 0, stream>>>(outp, Wt_out, b_out, out);
}